// Round 1
// baseline (726.802 us; speedup 1.0000x reference)
//
#include <hip/hip_runtime.h>

// ---------------------------------------------------------------------------
// SparseAttention: x @ Wqkv^T -> top-k(204/2048) masked softmax attn -> @ Wout^T
// b=2 n=2048 d=1024 h=16 dh=64, scale = 1/32, k_top = 204.
// Pipeline: cast f32->bf16, MFMA QKV-GEMM (q scaled, v relu'd+transposed),
// per-16-query-tile attention with full dots row in LDS + 2-level histogram
// threshold select, MFMA PV, MFMA output GEMM (+bias, f32 out).
// ---------------------------------------------------------------------------

using bf16x8 = __attribute__((ext_vector_type(8))) __bf16;
using u16x8  = __attribute__((ext_vector_type(8))) unsigned short;
using f32x4  = __attribute__((ext_vector_type(4))) float;

#define MFMA16(a, b, c) __builtin_amdgcn_mfma_f32_16x16x32_bf16(a, b, c, 0, 0, 0)

__device__ __forceinline__ unsigned short f2bf(float f) {
  return __builtin_bit_cast(unsigned short, (__bf16)f);
}

__device__ __forceinline__ float wred_max(float v) {
#pragma unroll
  for (int off = 32; off > 0; off >>= 1) v = fmaxf(v, __shfl_xor(v, off));
  return v;
}
__device__ __forceinline__ float wred_min(float v) {
#pragma unroll
  for (int off = 32; off > 0; off >>= 1) v = fminf(v, __shfl_xor(v, off));
  return v;
}
__device__ __forceinline__ float wred_sum(float v) {
#pragma unroll
  for (int off = 32; off > 0; off >>= 1) v += __shfl_xor(v, off);
  return v;
}

// Given a 256-bin histogram (per-wave, in LDS) and a rank (1-based, from the
// top), return the bin index of the rank-th largest element and the count of
// elements strictly above that bin.
__device__ __forceinline__ int hist_select(const unsigned int* hw, int lane,
                                           int rank, int* cntAbove) {
  unsigned int S = hw[4 * lane] + hw[4 * lane + 1] + hw[4 * lane + 2] + hw[4 * lane + 3];
#pragma unroll
  for (int off = 1; off < 64; off <<= 1) {
    unsigned int v = (unsigned int)__shfl_down((int)S, off);
    if (lane + off < 64) S += v;
  }
  unsigned long long ball = __ballot((int)S >= rank);
  int lstar = 63 - __builtin_clzll(ball);
  unsigned int Sst = (unsigned int)__shfl((int)S, lstar);
  unsigned int h0 = hw[4 * lstar], h1 = hw[4 * lstar + 1];
  unsigned int h2 = hw[4 * lstar + 2], h3 = hw[4 * lstar + 3];
  unsigned int g = Sst - h0 - h1 - h2 - h3;  // count in bins > 4*lstar+3
  int bb; unsigned int ca;
  if ((int)(g + h3) >= rank)                   { bb = 4 * lstar + 3; ca = g; }
  else if ((int)(g + h3 + h2) >= rank)         { bb = 4 * lstar + 2; ca = g + h3; }
  else if ((int)(g + h3 + h2 + h1) >= rank)    { bb = 4 * lstar + 1; ca = g + h3 + h2; }
  else                                         { bb = 4 * lstar;     ca = g + h3 + h2 + h1; }
  *cntAbove = (int)ca;
  return bb;
}

// ---------------- cast f32 -> bf16 (x4 vectorized) ----------------
__global__ void cast_f32_bf16(const float* __restrict__ s,
                              unsigned short* __restrict__ d, int n4) {
  int i = blockIdx.x * blockDim.x + threadIdx.x;
  int stride = gridDim.x * blockDim.x;
  for (; i < n4; i += stride) {
    float4 v = ((const float4*)s)[i];
    ushort4 o;
    o.x = f2bf(v.x); o.y = f2bf(v.y); o.z = f2bf(v.z); o.w = f2bf(v.w);
    ((ushort4*)d)[i] = o;
  }
}

// ---------------- GEMM1: qkv = x @ Wqkv^T, scatter to q/k/v^T ----------------
// A [4096][1024] bf16, W [3072][1024] bf16.
// q: [32][2048][64] (scaled 1/32), k: [32][2048][64], vt: [32][64][2048] (relu)
__global__ __launch_bounds__(256, 2) void gemm_qkv(
    const unsigned short* __restrict__ A, const unsigned short* __restrict__ W,
    unsigned short* __restrict__ qo, unsigned short* __restrict__ ko,
    unsigned short* __restrict__ vto) {
  const int K = 1024;
  __shared__ unsigned short As[128 * 32];
  __shared__ unsigned short Bs[128 * 32];
  int t = threadIdx.x;
  int m0 = blockIdx.y * 128, n0 = blockIdx.x * 128;
  int lane = t & 63, wave = t >> 6;
  int wm = wave >> 1, wn = wave & 1;
  int rs = t >> 2, cs = t & 3;
  int cl = cs ^ ((rs >> 1) & 3);  // XOR-swizzled content block (16B units)
  const unsigned short* pa0 = A + (size_t)(m0 + rs) * K + cl * 8;
  const unsigned short* pa1 = A + (size_t)(m0 + rs + 64) * K + cl * 8;
  const unsigned short* pb0 = W + (size_t)(n0 + rs) * K + cl * 8;
  const unsigned short* pb1 = W + (size_t)(n0 + rs + 64) * K + cl * 8;
  u16x8 ra0 = *(const u16x8*)pa0;
  u16x8 ra1 = *(const u16x8*)pa1;
  u16x8 rb0 = *(const u16x8*)pb0;
  u16x8 rb1 = *(const u16x8*)pb1;
  f32x4 zz = {0.f, 0.f, 0.f, 0.f};
  f32x4 acc[4][4];
#pragma unroll
  for (int i = 0; i < 4; ++i)
#pragma unroll
    for (int j = 0; j < 4; ++j) acc[i][j] = zz;
  int rr = lane & 15, cc = lane >> 4;
  int slot = (cc ^ ((rr >> 1) & 3)) * 8;
  for (int kt = 0; kt < K; kt += 32) {
    __syncthreads();
    *(u16x8*)&As[rs * 32 + cs * 8] = ra0;
    *(u16x8*)&As[(rs + 64) * 32 + cs * 8] = ra1;
    *(u16x8*)&Bs[rs * 32 + cs * 8] = rb0;
    *(u16x8*)&Bs[(rs + 64) * 32 + cs * 8] = rb1;
    if (kt + 32 < K) {  // prefetch next K-tile into regs, overlaps compute
      ra0 = *(const u16x8*)(pa0 + kt + 32);
      ra1 = *(const u16x8*)(pa1 + kt + 32);
      rb0 = *(const u16x8*)(pb0 + kt + 32);
      rb1 = *(const u16x8*)(pb1 + kt + 32);
    }
    __syncthreads();
    bf16x8 af[4], bfr[4];
#pragma unroll
    for (int f = 0; f < 4; ++f) {
      af[f]  = *(const bf16x8*)&As[(wm * 64 + f * 16 + rr) * 32 + slot];
      bfr[f] = *(const bf16x8*)&Bs[(wn * 64 + f * 16 + rr) * 32 + slot];
    }
#pragma unroll
    for (int fi = 0; fi < 4; ++fi)
#pragma unroll
      for (int fj = 0; fj < 4; ++fj)
        acc[fi][fj] = MFMA16(af[fi], bfr[fj], acc[fi][fj]);
  }
  int sub = n0 >> 10;  // 0=q 1=k 2=v (tile never crosses boundary)
#pragma unroll
  for (int fi = 0; fi < 4; ++fi) {
#pragma unroll
    for (int fj = 0; fj < 4; ++fj) {
#pragma unroll
      for (int r = 0; r < 4; ++r) {
        int m = m0 + wm * 64 + fi * 16 + cc * 4 + r;
        int n = n0 + wn * 64 + fj * 16 + rr;
        float v = acc[fi][fj][r];
        int b = m >> 11, nq = m & 2047;
        int e = n & 1023, hh = e >> 6, dh = e & 63;
        size_t bh = (size_t)(b * 16 + hh);
        if (sub == 0)      qo[(bh * 2048 + nq) * 64 + dh] = f2bf(v * 0.03125f);
        else if (sub == 1) ko[(bh * 2048 + nq) * 64 + dh] = f2bf(v);
        else               vto[(bh * 64 + dh) * 2048 + nq] = f2bf(fmaxf(v, 0.f));
      }
    }
  }
}

// ---------------- GEMM2: out = attn_out @ Wout^T + bias (f32 out) ----------------
__global__ __launch_bounds__(256, 2) void gemm_out(
    const unsigned short* __restrict__ A, const unsigned short* __restrict__ W,
    const float* __restrict__ bias, float* __restrict__ out) {
  const int K = 1024;
  __shared__ unsigned short As[128 * 32];
  __shared__ unsigned short Bs[128 * 32];
  int t = threadIdx.x;
  int m0 = blockIdx.y * 128, n0 = blockIdx.x * 128;
  int lane = t & 63, wave = t >> 6;
  int wm = wave >> 1, wn = wave & 1;
  int rs = t >> 2, cs = t & 3;
  int cl = cs ^ ((rs >> 1) & 3);
  const unsigned short* pa0 = A + (size_t)(m0 + rs) * K + cl * 8;
  const unsigned short* pa1 = A + (size_t)(m0 + rs + 64) * K + cl * 8;
  const unsigned short* pb0 = W + (size_t)(n0 + rs) * K + cl * 8;
  const unsigned short* pb1 = W + (size_t)(n0 + rs + 64) * K + cl * 8;
  u16x8 ra0 = *(const u16x8*)pa0;
  u16x8 ra1 = *(const u16x8*)pa1;
  u16x8 rb0 = *(const u16x8*)pb0;
  u16x8 rb1 = *(const u16x8*)pb1;
  f32x4 zz = {0.f, 0.f, 0.f, 0.f};
  f32x4 acc[4][4];
#pragma unroll
  for (int i = 0; i < 4; ++i)
#pragma unroll
    for (int j = 0; j < 4; ++j) acc[i][j] = zz;
  int rr = lane & 15, cc = lane >> 4;
  int slot = (cc ^ ((rr >> 1) & 3)) * 8;
  for (int kt = 0; kt < K; kt += 32) {
    __syncthreads();
    *(u16x8*)&As[rs * 32 + cs * 8] = ra0;
    *(u16x8*)&As[(rs + 64) * 32 + cs * 8] = ra1;
    *(u16x8*)&Bs[rs * 32 + cs * 8] = rb0;
    *(u16x8*)&Bs[(rs + 64) * 32 + cs * 8] = rb1;
    if (kt + 32 < K) {
      ra0 = *(const u16x8*)(pa0 + kt + 32);
      ra1 = *(const u16x8*)(pa1 + kt + 32);
      rb0 = *(const u16x8*)(pb0 + kt + 32);
      rb1 = *(const u16x8*)(pb1 + kt + 32);
    }
    __syncthreads();
    bf16x8 af[4], bfr[4];
#pragma unroll
    for (int f = 0; f < 4; ++f) {
      af[f]  = *(const bf16x8*)&As[(wm * 64 + f * 16 + rr) * 32 + slot];
      bfr[f] = *(const bf16x8*)&Bs[(wn * 64 + f * 16 + rr) * 32 + slot];
    }
#pragma unroll
    for (int fi = 0; fi < 4; ++fi)
#pragma unroll
      for (int fj = 0; fj < 4; ++fj)
        acc[fi][fj] = MFMA16(af[fi], bfr[fj], acc[fi][fj]);
  }
#pragma unroll
  for (int fi = 0; fi < 4; ++fi) {
#pragma unroll
    for (int fj = 0; fj < 4; ++fj) {
#pragma unroll
      for (int r = 0; r < 4; ++r) {
        int m = m0 + wm * 64 + fi * 16 + cc * 4 + r;
        int n = n0 + wn * 64 + fj * 16 + rr;
        out[(size_t)m * 1024 + n] = acc[fi][fj][r] + bias[n];
      }
    }
  }
}

// ---------------- Attention: 16 queries/WG, full 2048 dots row in LDS ----------------
// Q [32][2048][64] (pre-scaled), K [32][2048][64], Vt [32][64][2048] (relu'd)
// O = attn_out [2][2048][1024] bf16  ([b][n][h*64+dh])
__global__ __launch_bounds__(256, 1) void attn_kernel(
    const unsigned short* __restrict__ Q, const unsigned short* __restrict__ Kt,
    const unsigned short* __restrict__ Vt, unsigned short* __restrict__ O) {
  const int N = 2048, DS = 2052;  // DS % 32 == 4: 16B-aligned rows + bank spread
  __shared__ float dots[16 * DS];         // 131328 B, later reused as P (f32)
  __shared__ unsigned int hist[4][256];   // per-wave histogram
  __shared__ float s_sh[16];
  __shared__ float out_sh[16 * 68];       // padded to 68 for conflict-free atomics
  int bh = blockIdx.y;
  int q0 = blockIdx.x * 16;
  int t = threadIdx.x, lane = t & 63, wave = t >> 6;
  int rr = lane & 15, cc = lane >> 4;

  const unsigned short* Qh = Q + (size_t)bh * N * 64;
  const unsigned short* Kh = Kt + (size_t)bh * N * 64;
  const unsigned short* Vh = Vt + (size_t)bh * 64 * N;

  // Q fragments (A-operand): lane holds Q[q0+rr][cc*8 .. +8)
  bf16x8 aq0 = *(const bf16x8*)(Qh + (size_t)(q0 + rr) * 64 + cc * 8);
  bf16x8 aq1 = *(const bf16x8*)(Qh + (size_t)(q0 + rr) * 64 + 32 + cc * 8);

  // ---- phase 1: dots = Q K^T (scale folded into Q) ----
#pragma unroll 4
  for (int jb = wave; jb < 128; jb += 4) {
    const unsigned short* kp = Kh + (size_t)(jb * 16 + rr) * 64 + cc * 8;
    bf16x8 kb0 = *(const bf16x8*)(kp);
    bf16x8 kb1 = *(const bf16x8*)(kp + 32);
    f32x4 acc = {0.f, 0.f, 0.f, 0.f};
    acc = MFMA16(aq0, kb0, acc);
    acc = MFMA16(aq1, kb1, acc);
    int col = jb * 16 + rr;
#pragma unroll
    for (int r = 0; r < 4; ++r) dots[(cc * 4 + r) * DS + col] = acc[r];
  }
  for (int i = t; i < 16 * 68; i += 256) out_sh[i] = 0.f;
  __syncthreads();

  // ---- phase 2: per-row threshold select + softmax (P written in-place, f32) ----
  const int KTOP = 204;  // max(1, int(0.1 * 2048))
#pragma unroll 1
  for (int rw = 0; rw < 4; ++rw) {
    int row = wave * 4 + rw;
    float vals[32];
#pragma unroll
    for (int k2 = 0; k2 < 32; ++k2) vals[k2] = dots[row * DS + lane + 64 * k2];
    float vmax = vals[0], vmin = vals[0];
#pragma unroll
    for (int k2 = 1; k2 < 32; ++k2) {
      vmax = fmaxf(vmax, vals[k2]);
      vmin = fminf(vmin, vals[k2]);
    }
    vmax = wred_max(vmax);
    vmin = wred_min(vmin);
    float range = vmax - vmin;
    float thr;
    if (range < 1e-20f) {
      thr = vmin;
    } else {
      unsigned int* hw = hist[wave];
#pragma unroll
      for (int i = 0; i < 4; ++i) hw[lane * 4 + i] = 0;
      float sc1 = 256.0f / range;
#pragma unroll
      for (int k2 = 0; k2 < 32; ++k2) {
        int b1 = (int)((vals[k2] - vmin) * sc1);
        b1 = b1 > 255 ? 255 : b1;
        atomicAdd(&hw[b1], 1u);
      }
      asm volatile("s_waitcnt lgkmcnt(0)" ::: "memory");
      int cntAbove1;
      int bstar = hist_select(hw, lane, KTOP, &cntAbove1);
      int rank2 = KTOP - cntAbove1;  // >= 1
      float w1 = range * (1.0f / 256.0f);
      float lo2 = vmin + (float)bstar * w1;
#pragma unroll
      for (int i = 0; i < 4; ++i) hw[lane * 4 + i] = 0;
      float sc2 = 256.0f / w1;
#pragma unroll
      for (int k2 = 0; k2 < 32; ++k2) {
        int b1 = (int)((vals[k2] - vmin) * sc1);
        b1 = b1 > 255 ? 255 : b1;
        if (b1 == bstar) {
          int b2 = (int)((vals[k2] - lo2) * sc2);
          b2 = b2 < 0 ? 0 : (b2 > 255 ? 255 : b2);
          atomicAdd(&hw[b2], 1u);
        }
      }
      asm volatile("s_waitcnt lgkmcnt(0)" ::: "memory");
      int cntAbove2;
      int b2star = hist_select(hw, lane, rank2, &cntAbove2);
      thr = lo2 + (float)b2star * (w1 * (1.0f / 256.0f)) - range * 1e-7f;
    }
    float sum = 0.f;
#pragma unroll
    for (int k2 = 0; k2 < 32; ++k2) {
      float p = (vals[k2] >= thr) ? __expf(vals[k2] - vmax) : 0.f;
      sum += p;
      dots[row * DS + lane + 64 * k2] = p;  // in-place: own row only
    }
    sum = wred_sum(sum);
    if (lane == 0) s_sh[row] = sum;
  }
  __syncthreads();

  // ---- phase 3: out = P @ V (V pre-transposed, relu'd) ----
  f32x4 zz = {0.f, 0.f, 0.f, 0.f};
  f32x4 accp[4];
#pragma unroll
  for (int i = 0; i < 4; ++i) accp[i] = zz;
#pragma unroll 2
  for (int js = wave; js < 64; js += 4) {
    const float* pr = &dots[rr * DS + js * 32 + cc * 8];
    f32x4 p0 = *(const f32x4*)pr;
    f32x4 p1 = *(const f32x4*)(pr + 4);
    bf16x8 pa;
    pa[0] = (__bf16)p0[0]; pa[1] = (__bf16)p0[1];
    pa[2] = (__bf16)p0[2]; pa[3] = (__bf16)p0[3];
    pa[4] = (__bf16)p1[0]; pa[5] = (__bf16)p1[1];
    pa[6] = (__bf16)p1[2]; pa[7] = (__bf16)p1[3];
#pragma unroll
    for (int cb = 0; cb < 4; ++cb) {
      bf16x8 vb = *(const bf16x8*)(Vh + (size_t)(cb * 16 + rr) * N + js * 32 + cc * 8);
      accp[cb] = MFMA16(pa, vb, accp[cb]);
    }
  }
#pragma unroll
  for (int cb = 0; cb < 4; ++cb)
#pragma unroll
    for (int r = 0; r < 4; ++r)
      atomicAdd(&out_sh[(cc * 4 + r) * 68 + cb * 16 + rr], accp[cb][r]);
  __syncthreads();

  int b = bh >> 4, hh = bh & 15;
  for (int i = t; i < 1024; i += 256) {
    int q = i >> 6, d = i & 63;
    float v = out_sh[q * 68 + d] / s_sh[q];
    O[((size_t)(b * 2048 + q0 + q)) * 1024 + hh * 64 + d] = f2bf(v);
  }
}

// ---------------------------------------------------------------------------
extern "C" void kernel_launch(void* const* d_in, const int* in_sizes, int n_in,
                              void* d_out, int out_size, void* d_ws,
                              size_t ws_size, hipStream_t stream) {
  (void)in_sizes; (void)n_in; (void)out_size; (void)ws_size;
  const float* x    = (const float*)d_in[0];
  const float* Wqkv = (const float*)d_in[1];
  const float* Wout = (const float*)d_in[2];
  const float* bout = (const float*)d_in[3];
  float* out = (float*)d_out;

  char* ws = (char*)d_ws;
  unsigned short* x_bf  = (unsigned short*)(ws);                    //  8,388,608
  unsigned short* wq_bf = (unsigned short*)(ws + 8388608);          //  6,291,456
  unsigned short* wo_bf = (unsigned short*)(ws + 14680064);         //  2,097,152
  unsigned short* q_bf  = (unsigned short*)(ws + 16777216);         //  8,388,608
  unsigned short* k_bf  = (unsigned short*)(ws + 25165824);         //  8,388,608
  unsigned short* vt_bf = (unsigned short*)(ws + 33554432);         //  8,388,608
  unsigned short* ao_bf = (unsigned short*)(ws + 41943040);         //  8,388,608
  // total ws use: 50,331,648 bytes

  cast_f32_bf16<<<2048, 256, 0, stream>>>(x, x_bf, 1048576);
  cast_f32_bf16<<<1536, 256, 0, stream>>>(Wqkv, wq_bf, 786432);
  cast_f32_bf16<<<512, 256, 0, stream>>>(Wout, wo_bf, 262144);
  gemm_qkv<<<dim3(24, 32), 256, 0, stream>>>(x_bf, wq_bf, q_bf, k_bf, vt_bf);
  attn_kernel<<<dim3(128, 32), 256, 0, stream>>>(q_bf, k_bf, vt_bf, ao_bf);
  gemm_out<<<dim3(8, 32), 256, 0, stream>>>(ao_bf, wo_bf, bout, out);
}

// Round 4
// 494.931 us; speedup vs baseline: 1.4685x; 1.4685x over previous
//
#include <hip/hip_runtime.h>

// ---------------------------------------------------------------------------
// SparseAttention v2: all-f16 MFMA pipeline.
// x @ Wqkv^T -> top-k(204/2048) masked softmax attn -> @ Wout^T
// b=2 n=2048 d=1024 h=16 dh=64, scale=1/32 (folded into Wqkv cast), k_top=204.
// attn: 16 queries/WG, dots tile in LDS as f16 (66 KB -> 2 WG/CU), exact
// radix top-k select on f16 bit-keys, per-wave dh-block PV (no atomics).
// ---------------------------------------------------------------------------

using f16x8 = __attribute__((ext_vector_type(8))) _Float16;
using u16x8 = __attribute__((ext_vector_type(8))) unsigned short;
using f32x4 = __attribute__((ext_vector_type(4))) float;

#define MFMA16F(a, b, c) __builtin_amdgcn_mfma_f32_16x16x32_f16(a, b, c, 0, 0, 0)

__device__ __forceinline__ unsigned short f2h(float f) {
  return __builtin_bit_cast(unsigned short, (_Float16)f);
}
__device__ __forceinline__ float h2f(unsigned int u) {
  return (float)__builtin_bit_cast(_Float16, (unsigned short)u);
}
// monotone f16-bits -> u16 key (larger key == larger value)
__device__ __forceinline__ unsigned int key16(unsigned int u) {
  return (u & 0x8000u) ? (~u & 0xFFFFu) : (u | 0x8000u);
}
__device__ __forceinline__ unsigned int inv_key16(unsigned int k) {
  return (k & 0x8000u) ? (k & 0x7FFFu) : (~k & 0xFFFFu);
}
__device__ __forceinline__ float wred_sum(float v) {
#pragma unroll
  for (int off = 32; off > 0; off >>= 1) v += __shfl_xor(v, off);
  return v;
}

// rank-th largest bin (1-based from top) over a 256-bin histogram.
__device__ __forceinline__ int hist_select(const unsigned int* hw, int lane,
                                           int rank, int* cntAbove) {
  unsigned int S = hw[4 * lane] + hw[4 * lane + 1] + hw[4 * lane + 2] + hw[4 * lane + 3];
#pragma unroll
  for (int off = 1; off < 64; off <<= 1) {
    unsigned int v = (unsigned int)__shfl_down((int)S, off);
    if (lane + off < 64) S += v;
  }
  unsigned long long ball = __ballot((int)S >= rank);
  int lstar = 63 - __builtin_clzll(ball);
  unsigned int Sst = (unsigned int)__shfl((int)S, lstar);
  unsigned int h0 = hw[4 * lstar], h1 = hw[4 * lstar + 1];
  unsigned int h2 = hw[4 * lstar + 2], h3 = hw[4 * lstar + 3];
  unsigned int g = Sst - h0 - h1 - h2 - h3;
  int bb; unsigned int ca;
  if ((int)(g + h3) >= rank)                { bb = 4 * lstar + 3; ca = g; }
  else if ((int)(g + h3 + h2) >= rank)      { bb = 4 * lstar + 2; ca = g + h3; }
  else if ((int)(g + h3 + h2 + h1) >= rank) { bb = 4 * lstar + 1; ca = g + h3 + h2; }
  else                                      { bb = 4 * lstar;     ca = g + h3 + h2 + h1; }
  *cntAbove = (int)ca;
  return bb;
}

// ---------------- cast f32 -> f16 (x4), optional 1/32 scale for first scaleN4 ----
__global__ void cast_f32_f16(const float* __restrict__ s,
                             unsigned short* __restrict__ d, int n4, int scaleN4) {
  int i = blockIdx.x * blockDim.x + threadIdx.x;
  int stride = gridDim.x * blockDim.x;
  for (; i < n4; i += stride) {
    float4 v = ((const float4*)s)[i];
    float sc = (i < scaleN4) ? 0.03125f : 1.0f;
    ushort4 o;
    o.x = f2h(v.x * sc); o.y = f2h(v.y * sc); o.z = f2h(v.z * sc); o.w = f2h(v.w * sc);
    ((ushort4*)d)[i] = o;
  }
}

// ---------------- GEMM1: qkv[4096][3072] = x @ Wqkv^T (f16, coalesced) -------
__global__ __launch_bounds__(256, 2) void gemm_qkv(
    const unsigned short* __restrict__ A, const unsigned short* __restrict__ W,
    unsigned short* __restrict__ out) {
  const int K = 1024;
  __shared__ unsigned short As[128 * 32];
  __shared__ unsigned short Bs[128 * 32];
  int t = threadIdx.x;
  int m0 = blockIdx.y * 128, n0 = blockIdx.x * 128;
  int lane = t & 63, wave = t >> 6;
  int wm = wave >> 1, wn = wave & 1;
  int rs = t >> 2, cs = t & 3;
  int cl = cs ^ ((rs >> 1) & 3);
  const unsigned short* pa0 = A + (size_t)(m0 + rs) * K + cl * 8;
  const unsigned short* pa1 = A + (size_t)(m0 + rs + 64) * K + cl * 8;
  const unsigned short* pb0 = W + (size_t)(n0 + rs) * K + cl * 8;
  const unsigned short* pb1 = W + (size_t)(n0 + rs + 64) * K + cl * 8;
  u16x8 ra0 = *(const u16x8*)pa0;
  u16x8 ra1 = *(const u16x8*)pa1;
  u16x8 rb0 = *(const u16x8*)pb0;
  u16x8 rb1 = *(const u16x8*)pb1;
  f32x4 zz = {0.f, 0.f, 0.f, 0.f};
  f32x4 acc[4][4];
#pragma unroll
  for (int i = 0; i < 4; ++i)
#pragma unroll
    for (int j = 0; j < 4; ++j) acc[i][j] = zz;
  int rr = lane & 15, cc = lane >> 4;
  int slot = (cc ^ ((rr >> 1) & 3)) * 8;
  for (int kt = 0; kt < K; kt += 32) {
    __syncthreads();
    *(u16x8*)&As[rs * 32 + cs * 8] = ra0;
    *(u16x8*)&As[(rs + 64) * 32 + cs * 8] = ra1;
    *(u16x8*)&Bs[rs * 32 + cs * 8] = rb0;
    *(u16x8*)&Bs[(rs + 64) * 32 + cs * 8] = rb1;
    if (kt + 32 < K) {
      ra0 = *(const u16x8*)(pa0 + kt + 32);
      ra1 = *(const u16x8*)(pa1 + kt + 32);
      rb0 = *(const u16x8*)(pb0 + kt + 32);
      rb1 = *(const u16x8*)(pb1 + kt + 32);
    }
    __syncthreads();
    f16x8 af[4], bfr[4];
#pragma unroll
    for (int f = 0; f < 4; ++f) {
      af[f]  = *(const f16x8*)&As[(wm * 64 + f * 16 + rr) * 32 + slot];
      bfr[f] = *(const f16x8*)&Bs[(wn * 64 + f * 16 + rr) * 32 + slot];
    }
#pragma unroll
    for (int fi = 0; fi < 4; ++fi)
#pragma unroll
      for (int fj = 0; fj < 4; ++fj)
        acc[fi][fj] = MFMA16F(bfr[fj], af[fi], acc[fi][fj]);  // swapped: C[n][m]
  }
#pragma unroll
  for (int fi = 0; fi < 4; ++fi) {
#pragma unroll
    for (int fj = 0; fj < 4; ++fj) {
      int m = m0 + wm * 64 + fi * 16 + rr;
      int n = n0 + wn * 64 + fj * 16 + cc * 4;
      ushort4 pk;
      pk.x = f2h(acc[fi][fj][0]); pk.y = f2h(acc[fi][fj][1]);
      pk.z = f2h(acc[fi][fj][2]); pk.w = f2h(acc[fi][fj][3]);
      *(ushort4*)&out[(size_t)m * 3072 + n] = pk;
    }
  }
}

// ---------------- V transpose + relu: vt[bh][64][2048] <- qkv v-part --------
__global__ __launch_bounds__(256) void vtrans(const unsigned short* __restrict__ qkv,
                                              unsigned short* __restrict__ vt) {
  __shared__ unsigned short tile[64][72];
  int q0 = blockIdx.x * 64;
  int bh = blockIdx.y;
  int b = bh >> 4, h = bh & 15;
  int t = threadIdx.x;
  int r = t >> 2, seg = t & 3;
  const unsigned short* src =
      qkv + (size_t)(b * 2048 + q0 + r) * 3072 + 2048 + h * 64 + seg * 16;
  *(u16x8*)&tile[r][seg * 16]     = *(const u16x8*)src;
  *(u16x8*)&tile[r][seg * 16 + 8] = *(const u16x8*)(src + 8);
  __syncthreads();
  int dh = t & 63, qs = t >> 6;
  unsigned short vals[16];
#pragma unroll
  for (int j = 0; j < 16; ++j) {
    unsigned short v = tile[qs * 16 + j][dh];
    vals[j] = (v & 0x8000) ? (unsigned short)0 : v;  // relu on f16 bits
  }
  unsigned short* dst = vt + (size_t)(bh * 64 + dh) * 2048 + q0 + qs * 16;
  *(u16x8*)&dst[0] = *(u16x8*)&vals[0];
  *(u16x8*)&dst[8] = *(u16x8*)&vals[8];
}

// ---------------- Attention v2 ----------------------------------------------
// qkv [4096][3072] f16 (q pre-scaled), vt [32][64][2048] f16 (relu'd)
// O = ao [4096][1024] f16
#define DSF 2068  // f16 units per dots row (uint stride 1034: odd*2 -> bank spread)
__global__ __launch_bounds__(256, 2) void attn2(
    const unsigned short* __restrict__ qkv, const unsigned short* __restrict__ Vt,
    unsigned short* __restrict__ O) {
  __shared__ unsigned short dotsH[16 * DSF];  // 66,176 B
  __shared__ unsigned int hist[4][256];       //  4,096 B
  __shared__ float s_sh[16];
  int L = blockIdx.x;                 // 4096 linear; XCD-grouped: 4 bh per XCD
  int xcd = L & 7, idx = L >> 3;
  int bh = xcd * 4 + (idx >> 7);
  int q0 = (idx & 127) << 4;
  int b = bh >> 4, h = bh & 15;
  int t = threadIdx.x, lane = t & 63, wave = t >> 6;
  int rr = lane & 15, cc = lane >> 4;

  const unsigned short* qbase = qkv + (size_t)(b * 2048) * 3072 + h * 64;
  const unsigned short* kbase = qkv + (size_t)(b * 2048) * 3072 + 1024 + h * 64;
  const unsigned short* Vh = Vt + (size_t)bh * 64 * 2048;

  f16x8 aq0 = *(const f16x8*)(qbase + (size_t)(q0 + rr) * 3072 + cc * 8);
  f16x8 aq1 = *(const f16x8*)(qbase + (size_t)(q0 + rr) * 3072 + 32 + cc * 8);

  // ---- phase 1: dots = Q K^T (swapped mfma -> lane holds 4 consecutive keys) ----
#pragma unroll 2
  for (int jb = wave; jb < 128; jb += 4) {
    const unsigned short* kp = kbase + (size_t)(jb * 16 + rr) * 3072 + cc * 8;
    f16x8 kb0 = *(const f16x8*)(kp);
    f16x8 kb1 = *(const f16x8*)(kp + 32);
    f32x4 acc = {0.f, 0.f, 0.f, 0.f};
    acc = MFMA16F(kb0, aq0, acc);
    acc = MFMA16F(kb1, aq1, acc);
    // C: col=rr -> query, row=cc*4+r -> key within 16-tile
    ushort4 pk;
    pk.x = f2h(acc[0]); pk.y = f2h(acc[1]); pk.z = f2h(acc[2]); pk.w = f2h(acc[3]);
    *(ushort4*)&dotsH[rr * DSF + jb * 16 + cc * 4] = pk;
  }
  __syncthreads();

  // ---- phase 2: exact radix top-k on f16 keys + softmax (in-place) ----
  const int KTOP = 204;
#pragma unroll 1
  for (int rw = 0; rw < 4; ++rw) {
    int row = wave * 4 + rw;
    const unsigned int* rp = (const unsigned int*)(dotsH + row * DSF);
    unsigned int bits[16];
#pragma unroll
    for (int k = 0; k < 16; ++k) bits[k] = rp[lane + 64 * k];
    unsigned int* hw = hist[wave];
#pragma unroll
    for (int i = 0; i < 4; ++i) hw[lane * 4 + i] = 0;
    int kmax = 0;
#pragma unroll
    for (int k = 0; k < 16; ++k) {
      unsigned int k0 = key16(bits[k] & 0xFFFFu);
      unsigned int k1 = key16(bits[k] >> 16);
      int kk = (int)(k0 > k1 ? k0 : k1);
      kmax = kmax > kk ? kmax : kk;
      atomicAdd(&hw[k0 >> 8], 1u);
      atomicAdd(&hw[k1 >> 8], 1u);
    }
    asm volatile("s_waitcnt lgkmcnt(0)" ::: "memory");
    int cntAbove1;
    int bstar = hist_select(hw, lane, KTOP, &cntAbove1);
    int rank2 = KTOP - cntAbove1;
#pragma unroll
    for (int i = 0; i < 4; ++i) hw[lane * 4 + i] = 0;
#pragma unroll
    for (int k = 0; k < 16; ++k) {
      unsigned int k0 = key16(bits[k] & 0xFFFFu);
      unsigned int k1 = key16(bits[k] >> 16);
      if ((int)(k0 >> 8) == bstar) atomicAdd(&hw[k0 & 255u], 1u);
      if ((int)(k1 >> 8) == bstar) atomicAdd(&hw[k1 & 255u], 1u);
    }
    asm volatile("s_waitcnt lgkmcnt(0)" ::: "memory");
    int cntAbove2;
    int b2 = hist_select(hw, lane, rank2, &cntAbove2);
    unsigned int thrKey = ((unsigned int)bstar << 8) | (unsigned int)b2;
#pragma unroll
    for (int off = 32; off > 0; off >>= 1) {
      int o = __shfl_xor(kmax, off);
      kmax = kmax > o ? kmax : o;
    }
    float vmax = h2f(inv_key16((unsigned int)kmax));
    float sum = 0.f;
    unsigned int* wp = (unsigned int*)(dotsH + row * DSF);
#pragma unroll
    for (int k = 0; k < 16; ++k) {
      unsigned int u0 = bits[k] & 0xFFFFu, u1 = bits[k] >> 16;
      unsigned int k0 = key16(u0), k1 = key16(u1);
      float p0 = (k0 >= thrKey) ? __expf(h2f(u0) - vmax) : 0.f;
      float p1 = (k1 >= thrKey) ? __expf(h2f(u1) - vmax) : 0.f;
      sum += p0 + p1;
      wp[lane + 64 * k] = (unsigned int)f2h(p0) | ((unsigned int)f2h(p1) << 16);
    }
    sum = wred_sum(sum);
    if (lane == 0) s_sh[row] = sum;
  }
  __syncthreads();

  // ---- phase 3: out = P @ V, wave owns dh block [wave*16, wave*16+16) ----
  f32x4 accp = {0.f, 0.f, 0.f, 0.f};
  const unsigned short* vrow = Vh + (size_t)(wave * 16 + rr) * 2048;
#pragma unroll 4
  for (int js = 0; js < 64; ++js) {
    const unsigned short* pp = &dotsH[rr * DSF + js * 32 + cc * 8];
    uint2 lo = *(const uint2*)pp;
    uint2 hi = *(const uint2*)(pp + 4);
    uint4 tmp; tmp.x = lo.x; tmp.y = lo.y; tmp.z = hi.x; tmp.w = hi.y;
    f16x8 pa = __builtin_bit_cast(f16x8, tmp);
    f16x8 vb = *(const f16x8*)(vrow + js * 32 + cc * 8);
    accp = MFMA16F(pa, vb, accp);
  }
  // C: row=cc*4+r -> query, col=rr -> dh within block
#pragma unroll
  for (int r = 0; r < 4; ++r) {
    int q = cc * 4 + r;
    float v = accp[r] / s_sh[q];
    O[(size_t)(b * 2048 + q0 + q) * 1024 + h * 64 + wave * 16 + rr] = f2h(v);
  }
}

// ---------------- GEMM2: out = ao @ Wout^T + bias (f32 out, f32x4 stores) ----
__global__ __launch_bounds__(256, 2) void gemm_out(
    const unsigned short* __restrict__ A, const unsigned short* __restrict__ W,
    const float* __restrict__ bias, float* __restrict__ out) {
  const int K = 1024;
  __shared__ unsigned short As[128 * 32];
  __shared__ unsigned short Bs[128 * 32];
  int t = threadIdx.x;
  int m0 = blockIdx.y * 128, n0 = blockIdx.x * 128;
  int lane = t & 63, wave = t >> 6;
  int wm = wave >> 1, wn = wave & 1;
  int rs = t >> 2, cs = t & 3;
  int cl = cs ^ ((rs >> 1) & 3);
  const unsigned short* pa0 = A + (size_t)(m0 + rs) * K + cl * 8;
  const unsigned short* pa1 = A + (size_t)(m0 + rs + 64) * K + cl * 8;
  const unsigned short* pb0 = W + (size_t)(n0 + rs) * K + cl * 8;
  const unsigned short* pb1 = W + (size_t)(n0 + rs + 64) * K + cl * 8;
  u16x8 ra0 = *(const u16x8*)pa0;
  u16x8 ra1 = *(const u16x8*)pa1;
  u16x8 rb0 = *(const u16x8*)pb0;
  u16x8 rb1 = *(const u16x8*)pb1;
  f32x4 zz = {0.f, 0.f, 0.f, 0.f};
  f32x4 acc[4][4];
#pragma unroll
  for (int i = 0; i < 4; ++i)
#pragma unroll
    for (int j = 0; j < 4; ++j) acc[i][j] = zz;
  int rr = lane & 15, cc = lane >> 4;
  int slot = (cc ^ ((rr >> 1) & 3)) * 8;
  for (int kt = 0; kt < K; kt += 32) {
    __syncthreads();
    *(u16x8*)&As[rs * 32 + cs * 8] = ra0;
    *(u16x8*)&As[(rs + 64) * 32 + cs * 8] = ra1;
    *(u16x8*)&Bs[rs * 32 + cs * 8] = rb0;
    *(u16x8*)&Bs[(rs + 64) * 32 + cs * 8] = rb1;
    if (kt + 32 < K) {
      ra0 = *(const u16x8*)(pa0 + kt + 32);
      ra1 = *(const u16x8*)(pa1 + kt + 32);
      rb0 = *(const u16x8*)(pb0 + kt + 32);
      rb1 = *(const u16x8*)(pb1 + kt + 32);
    }
    __syncthreads();
    f16x8 af[4], bfr[4];
#pragma unroll
    for (int f = 0; f < 4; ++f) {
      af[f]  = *(const f16x8*)&As[(wm * 64 + f * 16 + rr) * 32 + slot];
      bfr[f] = *(const f16x8*)&Bs[(wn * 64 + f * 16 + rr) * 32 + slot];
    }
#pragma unroll
    for (int fi = 0; fi < 4; ++fi)
#pragma unroll
      for (int fj = 0; fj < 4; ++fj)
        acc[fi][fj] = MFMA16F(bfr[fj], af[fi], acc[fi][fj]);  // swapped
  }
#pragma unroll
  for (int fi = 0; fi < 4; ++fi) {
#pragma unroll
    for (int fj = 0; fj < 4; ++fj) {
      int m = m0 + wm * 64 + fi * 16 + rr;
      int n = n0 + wn * 64 + fj * 16 + cc * 4;
      f32x4 bv = *(const f32x4*)&bias[n];
      f32x4 o = acc[fi][fj] + bv;
      *(f32x4*)&out[(size_t)m * 1024 + n] = o;
    }
  }
}

// ---------------------------------------------------------------------------
extern "C" void kernel_launch(void* const* d_in, const int* in_sizes, int n_in,
                              void* d_out, int out_size, void* d_ws,
                              size_t ws_size, hipStream_t stream) {
  (void)in_sizes; (void)n_in; (void)out_size; (void)ws_size;
  const float* x    = (const float*)d_in[0];
  const float* Wqkv = (const float*)d_in[1];
  const float* Wout = (const float*)d_in[2];
  const float* bout = (const float*)d_in[3];
  float* out = (float*)d_out;

  char* ws = (char*)d_ws;
  unsigned short* x_h  = (unsigned short*)(ws);              // 8 MB; reused as ao
  unsigned short* ao   = (unsigned short*)(ws);
  unsigned short* wq_h = (unsigned short*)(ws + 8388608);    // 6 MB; reused as vt
  unsigned short* vt   = (unsigned short*)(ws + 8388608);    // 8 MB
  unsigned short* wo_h = (unsigned short*)(ws + 16777216);   // 2 MB
  unsigned short* qkv  = (unsigned short*)(ws + 18874368);   // 24 MB (end ~44 MB)

  cast_f32_f16<<<1024, 256, 0, stream>>>(x, x_h, 1048576, 0);
  cast_f32_f16<<<768, 256, 0, stream>>>(Wqkv, wq_h, 786432, 262144);
  cast_f32_f16<<<256, 256, 0, stream>>>(Wout, wo_h, 262144, 0);
  gemm_qkv<<<dim3(24, 32), 256, 0, stream>>>(x_h, wq_h, qkv);
  vtrans<<<dim3(32, 32), 256, 0, stream>>>(qkv, vt);
  attn2<<<4096, 256, 0, stream>>>(qkv, vt, ao);
  gemm_out<<<dim3(8, 32), 256, 0, stream>>>(ao, wo_h, bout, out);
}

// Round 5
// 447.042 us; speedup vs baseline: 1.6258x; 1.1071x over previous
//
#include <hip/hip_runtime.h>

// ---------------------------------------------------------------------------
// SparseAttention v3: all-f16 MFMA pipeline.
// x @ Wqkv^T -> top-k(204/2048) masked softmax attn -> @ Wout^T
// b=2 n=2048 d=1024 h=16 dh=64, scale=1/32 (folded into Wqkv cast), k_top=204.
// attn: 16 queries/WG, 512 threads (8 waves) share the tile -> per-WG serial
// chain halves vs v2 and occupancy doubles to 16 waves/CU. Dots tile f16 in
// LDS, exact radix top-k on f16 bit-keys, PV split across wave pairs with
// f32 LDS-atomic combine.
// ---------------------------------------------------------------------------

using f16x8 = __attribute__((ext_vector_type(8))) _Float16;
using u16x8 = __attribute__((ext_vector_type(8))) unsigned short;
using f32x4 = __attribute__((ext_vector_type(4))) float;

#define MFMA16F(a, b, c) __builtin_amdgcn_mfma_f32_16x16x32_f16(a, b, c, 0, 0, 0)

__device__ __forceinline__ unsigned short f2h(float f) {
  return __builtin_bit_cast(unsigned short, (_Float16)f);
}
__device__ __forceinline__ float h2f(unsigned int u) {
  return (float)__builtin_bit_cast(_Float16, (unsigned short)u);
}
// monotone f16-bits -> u16 key (larger key == larger value)
__device__ __forceinline__ unsigned int key16(unsigned int u) {
  return (u & 0x8000u) ? (~u & 0xFFFFu) : (u | 0x8000u);
}
__device__ __forceinline__ unsigned int inv_key16(unsigned int k) {
  return (k & 0x8000u) ? (k & 0x7FFFu) : (~k & 0xFFFFu);
}
__device__ __forceinline__ float wred_sum(float v) {
#pragma unroll
  for (int off = 32; off > 0; off >>= 1) v += __shfl_xor(v, off);
  return v;
}

// rank-th largest bin (1-based from top) over a 256-bin histogram.
__device__ __forceinline__ int hist_select(const unsigned int* hw, int lane,
                                           int rank, int* cntAbove) {
  unsigned int S = hw[4 * lane] + hw[4 * lane + 1] + hw[4 * lane + 2] + hw[4 * lane + 3];
#pragma unroll
  for (int off = 1; off < 64; off <<= 1) {
    unsigned int v = (unsigned int)__shfl_down((int)S, off);
    if (lane + off < 64) S += v;
  }
  unsigned long long ball = __ballot((int)S >= rank);
  int lstar = 63 - __builtin_clzll(ball);
  unsigned int Sst = (unsigned int)__shfl((int)S, lstar);
  unsigned int h0 = hw[4 * lstar], h1 = hw[4 * lstar + 1];
  unsigned int h2 = hw[4 * lstar + 2], h3 = hw[4 * lstar + 3];
  unsigned int g = Sst - h0 - h1 - h2 - h3;
  int bb; unsigned int ca;
  if ((int)(g + h3) >= rank)                { bb = 4 * lstar + 3; ca = g; }
  else if ((int)(g + h3 + h2) >= rank)      { bb = 4 * lstar + 2; ca = g + h3; }
  else if ((int)(g + h3 + h2 + h1) >= rank) { bb = 4 * lstar + 1; ca = g + h3 + h2; }
  else                                      { bb = 4 * lstar;     ca = g + h3 + h2 + h1; }
  *cntAbove = (int)ca;
  return bb;
}

// ---------------- cast f32 -> f16 (x4), optional 1/32 scale for first scaleN4 ----
__global__ void cast_f32_f16(const float* __restrict__ s,
                             unsigned short* __restrict__ d, int n4, int scaleN4) {
  int i = blockIdx.x * blockDim.x + threadIdx.x;
  int stride = gridDim.x * blockDim.x;
  for (; i < n4; i += stride) {
    float4 v = ((const float4*)s)[i];
    float sc = (i < scaleN4) ? 0.03125f : 1.0f;
    ushort4 o;
    o.x = f2h(v.x * sc); o.y = f2h(v.y * sc); o.z = f2h(v.z * sc); o.w = f2h(v.w * sc);
    ((ushort4*)d)[i] = o;
  }
}

// ---------------- GEMM1: qkv[4096][3072] = x @ Wqkv^T (f16, coalesced) -------
__global__ __launch_bounds__(256, 2) void gemm_qkv(
    const unsigned short* __restrict__ A, const unsigned short* __restrict__ W,
    unsigned short* __restrict__ out) {
  const int K = 1024;
  __shared__ unsigned short As[128 * 32];
  __shared__ unsigned short Bs[128 * 32];
  int t = threadIdx.x;
  int m0 = blockIdx.y * 128, n0 = blockIdx.x * 128;
  int lane = t & 63, wave = t >> 6;
  int wm = wave >> 1, wn = wave & 1;
  int rs = t >> 2, cs = t & 3;
  int cl = cs ^ ((rs >> 1) & 3);
  const unsigned short* pa0 = A + (size_t)(m0 + rs) * K + cl * 8;
  const unsigned short* pa1 = A + (size_t)(m0 + rs + 64) * K + cl * 8;
  const unsigned short* pb0 = W + (size_t)(n0 + rs) * K + cl * 8;
  const unsigned short* pb1 = W + (size_t)(n0 + rs + 64) * K + cl * 8;
  u16x8 ra0 = *(const u16x8*)pa0;
  u16x8 ra1 = *(const u16x8*)pa1;
  u16x8 rb0 = *(const u16x8*)pb0;
  u16x8 rb1 = *(const u16x8*)pb1;
  f32x4 zz = {0.f, 0.f, 0.f, 0.f};
  f32x4 acc[4][4];
#pragma unroll
  for (int i = 0; i < 4; ++i)
#pragma unroll
    for (int j = 0; j < 4; ++j) acc[i][j] = zz;
  int rr = lane & 15, cc = lane >> 4;
  int slot = (cc ^ ((rr >> 1) & 3)) * 8;
  for (int kt = 0; kt < K; kt += 32) {
    __syncthreads();
    *(u16x8*)&As[rs * 32 + cs * 8] = ra0;
    *(u16x8*)&As[(rs + 64) * 32 + cs * 8] = ra1;
    *(u16x8*)&Bs[rs * 32 + cs * 8] = rb0;
    *(u16x8*)&Bs[(rs + 64) * 32 + cs * 8] = rb1;
    if (kt + 32 < K) {
      ra0 = *(const u16x8*)(pa0 + kt + 32);
      ra1 = *(const u16x8*)(pa1 + kt + 32);
      rb0 = *(const u16x8*)(pb0 + kt + 32);
      rb1 = *(const u16x8*)(pb1 + kt + 32);
    }
    __syncthreads();
    f16x8 af[4], bfr[4];
#pragma unroll
    for (int f = 0; f < 4; ++f) {
      af[f]  = *(const f16x8*)&As[(wm * 64 + f * 16 + rr) * 32 + slot];
      bfr[f] = *(const f16x8*)&Bs[(wn * 64 + f * 16 + rr) * 32 + slot];
    }
#pragma unroll
    for (int fi = 0; fi < 4; ++fi)
#pragma unroll
      for (int fj = 0; fj < 4; ++fj)
        acc[fi][fj] = MFMA16F(bfr[fj], af[fi], acc[fi][fj]);  // swapped: C[n][m]
  }
#pragma unroll
  for (int fi = 0; fi < 4; ++fi) {
#pragma unroll
    for (int fj = 0; fj < 4; ++fj) {
      int m = m0 + wm * 64 + fi * 16 + rr;
      int n = n0 + wn * 64 + fj * 16 + cc * 4;
      ushort4 pk;
      pk.x = f2h(acc[fi][fj][0]); pk.y = f2h(acc[fi][fj][1]);
      pk.z = f2h(acc[fi][fj][2]); pk.w = f2h(acc[fi][fj][3]);
      *(ushort4*)&out[(size_t)m * 3072 + n] = pk;
    }
  }
}

// ---------------- V transpose + relu: vt[bh][64][2048] <- qkv v-part --------
__global__ __launch_bounds__(256) void vtrans(const unsigned short* __restrict__ qkv,
                                              unsigned short* __restrict__ vt) {
  __shared__ unsigned short tile[64][72];
  int q0 = blockIdx.x * 64;
  int bh = blockIdx.y;
  int b = bh >> 4, h = bh & 15;
  int t = threadIdx.x;
  int r = t >> 2, seg = t & 3;
  const unsigned short* src =
      qkv + (size_t)(b * 2048 + q0 + r) * 3072 + 2048 + h * 64 + seg * 16;
  *(u16x8*)&tile[r][seg * 16]     = *(const u16x8*)src;
  *(u16x8*)&tile[r][seg * 16 + 8] = *(const u16x8*)(src + 8);
  __syncthreads();
  int dh = t & 63, qs = t >> 6;
  unsigned short vals[16];
#pragma unroll
  for (int j = 0; j < 16; ++j) {
    unsigned short v = tile[qs * 16 + j][dh];
    vals[j] = (v & 0x8000) ? (unsigned short)0 : v;  // relu on f16 bits
  }
  unsigned short* dst = vt + (size_t)(bh * 64 + dh) * 2048 + q0 + qs * 16;
  *(u16x8*)&dst[0] = *(u16x8*)&vals[0];
  *(u16x8*)&dst[8] = *(u16x8*)&vals[8];
}

// ---------------- Attention v3: 512 threads (8 waves) per 16-query tile ------
// qkv [4096][3072] f16 (q pre-scaled), vt [32][64][2048] f16 (relu'd)
// O = ao [4096][1024] f16
#define DSF 2068  // f16 units per dots row (uint stride 1034 -> bank spread)
__global__ __launch_bounds__(512, 4) void attn3(
    const unsigned short* __restrict__ qkv, const unsigned short* __restrict__ Vt,
    unsigned short* __restrict__ O) {
  __shared__ unsigned short dotsH[16 * DSF];  // 66,176 B
  __shared__ unsigned int hist[8][256];       //  8,192 B
  __shared__ float s_sh[16];
  __shared__ float out_sh[16 * 68];           //  4,352 B (total ~78.8 KB)
  int L = blockIdx.x;                 // 4096 linear; XCD-grouped: 4 bh per XCD
  int xcd = L & 7, idx = L >> 3;
  int bh = xcd * 4 + (idx >> 7);
  int q0 = (idx & 127) << 4;
  int b = bh >> 4, h = bh & 15;
  int t = threadIdx.x, lane = t & 63, wave = t >> 6;  // wave in 0..7
  int rr = lane & 15, cc = lane >> 4;

  const unsigned short* qbase = qkv + (size_t)(b * 2048) * 3072 + h * 64;
  const unsigned short* kbase = qkv + (size_t)(b * 2048) * 3072 + 1024 + h * 64;
  const unsigned short* Vh = Vt + (size_t)bh * 64 * 2048;

  f16x8 aq0 = *(const f16x8*)(qbase + (size_t)(q0 + rr) * 3072 + cc * 8);
  f16x8 aq1 = *(const f16x8*)(qbase + (size_t)(q0 + rr) * 3072 + 32 + cc * 8);

  for (int i = t; i < 16 * 68; i += 512) out_sh[i] = 0.f;

  // ---- phase 1: dots = Q K^T, 16 jb-tiles per wave ----
#pragma unroll 2
  for (int jb = wave; jb < 128; jb += 8) {
    const unsigned short* kp = kbase + (size_t)(jb * 16 + rr) * 3072 + cc * 8;
    f16x8 kb0 = *(const f16x8*)(kp);
    f16x8 kb1 = *(const f16x8*)(kp + 32);
    f32x4 acc = {0.f, 0.f, 0.f, 0.f};
    acc = MFMA16F(kb0, aq0, acc);
    acc = MFMA16F(kb1, aq1, acc);
    // C: col=rr -> query, row=cc*4+r -> key within 16-tile
    ushort4 pk;
    pk.x = f2h(acc[0]); pk.y = f2h(acc[1]); pk.z = f2h(acc[2]); pk.w = f2h(acc[3]);
    *(ushort4*)&dotsH[rr * DSF + jb * 16 + cc * 4] = pk;
  }
  __syncthreads();

  // ---- phase 2: exact radix top-k on f16 keys + softmax, 2 rows per wave ----
  const int KTOP = 204;
#pragma unroll 1
  for (int rw = 0; rw < 2; ++rw) {
    int row = wave * 2 + rw;
    const unsigned int* rp = (const unsigned int*)(dotsH + row * DSF);
    unsigned int bits[16];
#pragma unroll
    for (int k = 0; k < 16; ++k) bits[k] = rp[lane + 64 * k];
    unsigned int* hw = hist[wave];
#pragma unroll
    for (int i = 0; i < 4; ++i) hw[lane * 4 + i] = 0;
    int kmax = 0;
#pragma unroll
    for (int k = 0; k < 16; ++k) {
      unsigned int k0 = key16(bits[k] & 0xFFFFu);
      unsigned int k1 = key16(bits[k] >> 16);
      int kk = (int)(k0 > k1 ? k0 : k1);
      kmax = kmax > kk ? kmax : kk;
      atomicAdd(&hw[k0 >> 8], 1u);
      atomicAdd(&hw[k1 >> 8], 1u);
    }
    asm volatile("s_waitcnt lgkmcnt(0)" ::: "memory");
    int cntAbove1;
    int bstar = hist_select(hw, lane, KTOP, &cntAbove1);
    int rank2 = KTOP - cntAbove1;
#pragma unroll
    for (int i = 0; i < 4; ++i) hw[lane * 4 + i] = 0;
#pragma unroll
    for (int k = 0; k < 16; ++k) {
      unsigned int k0 = key16(bits[k] & 0xFFFFu);
      unsigned int k1 = key16(bits[k] >> 16);
      if ((int)(k0 >> 8) == bstar) atomicAdd(&hw[k0 & 255u], 1u);
      if ((int)(k1 >> 8) == bstar) atomicAdd(&hw[k1 & 255u], 1u);
    }
    asm volatile("s_waitcnt lgkmcnt(0)" ::: "memory");
    int cntAbove2;
    int b2 = hist_select(hw, lane, rank2, &cntAbove2);
    unsigned int thrKey = ((unsigned int)bstar << 8) | (unsigned int)b2;
#pragma unroll
    for (int off = 32; off > 0; off >>= 1) {
      int o = __shfl_xor(kmax, off);
      kmax = kmax > o ? kmax : o;
    }
    float vmax = h2f(inv_key16((unsigned int)kmax));
    float sum = 0.f;
    unsigned int* wp = (unsigned int*)(dotsH + row * DSF);
#pragma unroll
    for (int k = 0; k < 16; ++k) {
      unsigned int u0 = bits[k] & 0xFFFFu, u1 = bits[k] >> 16;
      unsigned int k0 = key16(u0), k1 = key16(u1);
      float p0 = (k0 >= thrKey) ? __expf(h2f(u0) - vmax) : 0.f;
      float p1 = (k1 >= thrKey) ? __expf(h2f(u1) - vmax) : 0.f;
      sum += p0 + p1;
      wp[lane + 64 * k] = (unsigned int)f2h(p0) | ((unsigned int)f2h(p1) << 16);
    }
    sum = wred_sum(sum);
    if (lane == 0) s_sh[row] = sum;
  }
  __syncthreads();

  // ---- phase 3: out = P @ V; wave -> dh block (wave&3), js half (wave>>2) ----
  f32x4 accp = {0.f, 0.f, 0.f, 0.f};
  int db = wave & 3;
  int js0 = (wave >> 2) * 32;
  const unsigned short* vrow = Vh + (size_t)(db * 16 + rr) * 2048;
#pragma unroll 4
  for (int js = js0; js < js0 + 32; ++js) {
    const unsigned short* pp = &dotsH[rr * DSF + js * 32 + cc * 8];
    uint2 lo = *(const uint2*)pp;
    uint2 hi = *(const uint2*)(pp + 4);
    uint4 tmp; tmp.x = lo.x; tmp.y = lo.y; tmp.z = hi.x; tmp.w = hi.y;
    f16x8 pa = __builtin_bit_cast(f16x8, tmp);
    f16x8 vb = *(const f16x8*)(vrow + js * 32 + cc * 8);
    accp = MFMA16F(pa, vb, accp);
  }
  // C: row=cc*4+r -> query, col=rr -> dh within block; combine wave pairs in LDS
#pragma unroll
  for (int r = 0; r < 4; ++r) {
    int q = cc * 4 + r;
    atomicAdd(&out_sh[q * 68 + db * 16 + rr], accp[r]);
  }
  __syncthreads();

  for (int i = t; i < 1024; i += 512) {
    int q = i >> 6, d = i & 63;
    float v = out_sh[q * 68 + d] / s_sh[q];
    O[(size_t)(b * 2048 + q0 + q) * 1024 + h * 64 + d] = f2h(v);
  }
}

// ---------------- GEMM2: out = ao @ Wout^T + bias (f32 out, f32x4 stores) ----
__global__ __launch_bounds__(256, 2) void gemm_out(
    const unsigned short* __restrict__ A, const unsigned short* __restrict__ W,
    const float* __restrict__ bias, float* __restrict__ out) {
  const int K = 1024;
  __shared__ unsigned short As[128 * 32];
  __shared__ unsigned short Bs[128 * 32];
  int t = threadIdx.x;
  int m0 = blockIdx.y * 128, n0 = blockIdx.x * 128;
  int lane = t & 63, wave = t >> 6;
  int wm = wave >> 1, wn = wave & 1;
  int rs = t >> 2, cs = t & 3;
  int cl = cs ^ ((rs >> 1) & 3);
  const unsigned short* pa0 = A + (size_t)(m0 + rs) * K + cl * 8;
  const unsigned short* pa1 = A + (size_t)(m0 + rs + 64) * K + cl * 8;
  const unsigned short* pb0 = W + (size_t)(n0 + rs) * K + cl * 8;
  const unsigned short* pb1 = W + (size_t)(n0 + rs + 64) * K + cl * 8;
  u16x8 ra0 = *(const u16x8*)pa0;
  u16x8 ra1 = *(const u16x8*)pa1;
  u16x8 rb0 = *(const u16x8*)pb0;
  u16x8 rb1 = *(const u16x8*)pb1;
  f32x4 zz = {0.f, 0.f, 0.f, 0.f};
  f32x4 acc[4][4];
#pragma unroll
  for (int i = 0; i < 4; ++i)
#pragma unroll
    for (int j = 0; j < 4; ++j) acc[i][j] = zz;
  int rr = lane & 15, cc = lane >> 4;
  int slot = (cc ^ ((rr >> 1) & 3)) * 8;
  for (int kt = 0; kt < K; kt += 32) {
    __syncthreads();
    *(u16x8*)&As[rs * 32 + cs * 8] = ra0;
    *(u16x8*)&As[(rs + 64) * 32 + cs * 8] = ra1;
    *(u16x8*)&Bs[rs * 32 + cs * 8] = rb0;
    *(u16x8*)&Bs[(rs + 64) * 32 + cs * 8] = rb1;
    if (kt + 32 < K) {
      ra0 = *(const u16x8*)(pa0 + kt + 32);
      ra1 = *(const u16x8*)(pa1 + kt + 32);
      rb0 = *(const u16x8*)(pb0 + kt + 32);
      rb1 = *(const u16x8*)(pb1 + kt + 32);
    }
    __syncthreads();
    f16x8 af[4], bfr[4];
#pragma unroll
    for (int f = 0; f < 4; ++f) {
      af[f]  = *(const f16x8*)&As[(wm * 64 + f * 16 + rr) * 32 + slot];
      bfr[f] = *(const f16x8*)&Bs[(wn * 64 + f * 16 + rr) * 32 + slot];
    }
#pragma unroll
    for (int fi = 0; fi < 4; ++fi)
#pragma unroll
      for (int fj = 0; fj < 4; ++fj)
        acc[fi][fj] = MFMA16F(bfr[fj], af[fi], acc[fi][fj]);  // swapped
  }
#pragma unroll
  for (int fi = 0; fi < 4; ++fi) {
#pragma unroll
    for (int fj = 0; fj < 4; ++fj) {
      int m = m0 + wm * 64 + fi * 16 + rr;
      int n = n0 + wn * 64 + fj * 16 + cc * 4;
      f32x4 bv = *(const f32x4*)&bias[n];
      f32x4 o = acc[fi][fj] + bv;
      *(f32x4*)&out[(size_t)m * 1024 + n] = o;
    }
  }
}

// ---------------------------------------------------------------------------
extern "C" void kernel_launch(void* const* d_in, const int* in_sizes, int n_in,
                              void* d_out, int out_size, void* d_ws,
                              size_t ws_size, hipStream_t stream) {
  (void)in_sizes; (void)n_in; (void)out_size; (void)ws_size;
  const float* x    = (const float*)d_in[0];
  const float* Wqkv = (const float*)d_in[1];
  const float* Wout = (const float*)d_in[2];
  const float* bout = (const float*)d_in[3];
  float* out = (float*)d_out;

  char* ws = (char*)d_ws;
  unsigned short* x_h  = (unsigned short*)(ws);              // 8 MB; reused as ao
  unsigned short* ao   = (unsigned short*)(ws);
  unsigned short* wq_h = (unsigned short*)(ws + 8388608);    // 6 MB; reused as vt
  unsigned short* vt   = (unsigned short*)(ws + 8388608);    // 8 MB
  unsigned short* wo_h = (unsigned short*)(ws + 16777216);   // 2 MB
  unsigned short* qkv  = (unsigned short*)(ws + 18874368);   // 24 MB (end ~44 MB)

  cast_f32_f16<<<1024, 256, 0, stream>>>(x, x_h, 1048576, 0);
  cast_f32_f16<<<768, 256, 0, stream>>>(Wqkv, wq_h, 786432, 262144);
  cast_f32_f16<<<256, 256, 0, stream>>>(Wout, wo_h, 262144, 0);
  gemm_qkv<<<dim3(24, 32), 256, 0, stream>>>(x_h, wq_h, qkv);
  vtrans<<<dim3(32, 32), 256, 0, stream>>>(qkv, vt);
  attn3<<<4096, 512, 0, stream>>>(qkv, vt, ao);
  gemm_out<<<dim3(8, 32), 256, 0, stream>>>(ao, wo_h, bout, out);
}